// Round 1
// baseline (119.835 us; speedup 1.0000x reference)
//
#include <hip/hip_runtime.h>

// Problem constants
#define RES    128
#define P_PTS  4096
#define BATCH  8
#define PHASE  0.04908738521234052f   // 2*pi/128

// Workspace layout (in floats)
//  cbuf   : [P][B][2]        = 65,536 floats   (c[b,p]/128, interleaved re/im, p-major)
//  Ay     : [P][128][2]      = 1,048,576 floats
//  Ax     : [P][128][2]      = 1,048,576 floats
//  partial: [NCHUNK][B][128][128][2] = 16*262,144 = 4,194,304 floats
// total ~6.36M floats = 25.4 MB
#define OFF_C    0
#define OFF_AY   65536
#define OFF_AX   1114112
#define OFF_PART 2162688

#define NCHUNK 16
#define KC     (P_PTS / NCHUNK)   // 256 k-space points per chunk
#define KTILE  32

// ---------------------------------------------------------------------------
// Kernel 1: grid-sample -> c[b,p] (scaled by 1/RES), and phase tables Ax, Ay
// grid: P_PTS blocks, 128 threads (thread t = grid coordinate)
// ---------------------------------------------------------------------------
__global__ __launch_bounds__(128) void prep_kernel(const float* __restrict__ ksp,
                                                   const float* __restrict__ traj,
                                                   float* __restrict__ ws) {
    const int p = blockIdx.x;
    const int t = threadIdx.x;
    const float tx = traj[2 * p];
    const float ty = traj[2 * p + 1];
    const float xs = (float)t - 64.0f;

    float* Ax = ws + OFF_AX;
    float* Ay = ws + OFF_AY;
    const int off = (p * 128 + t) * 2;

    float s, c;
    __sincosf(PHASE * tx * xs, &s, &c);
    Ax[off] = c; Ax[off + 1] = s;
    __sincosf(PHASE * ty * xs, &s, &c);
    Ay[off] = c; Ay[off + 1] = s;

    if (t < BATCH) {
        const int b = t;
        // grid_sample, bilinear, zero padding, align_corners=False:
        // x = (traj_x/64 + 1)*64 - 0.5 = traj_x + 63.5
        const float x = tx + 63.5f;
        const float y = ty + 63.5f;
        const float x0f = floorf(x), y0f = floorf(y);
        const float wx = x - x0f, wy = y - y0f;
        const int ix0 = (int)x0f, iy0 = (int)y0f;
        float re = 0.0f, im = 0.0f;
#pragma unroll
        for (int dy = 0; dy < 2; ++dy) {
#pragma unroll
            for (int dx = 0; dx < 2; ++dx) {
                const int ix = ix0 + dx;
                const int iy = iy0 + dy;
                const float w = (dx ? wx : 1.0f - wx) * (dy ? wy : 1.0f - wy);
                if (ix >= 0 && ix < RES && iy >= 0 && iy < RES) {
                    const int base = ((b * RES + iy) * RES + ix) * 2;
                    re = fmaf(ksp[base],     w, re);
                    im = fmaf(ksp[base + 1], w, im);
                }
            }
        }
        float* cb = ws + OFF_C;
        cb[p * 16 + 2 * b]     = re * (1.0f / 128.0f);
        cb[p * 16 + 2 * b + 1] = im * (1.0f / 128.0f);
    }
}

// ---------------------------------------------------------------------------
// Kernel 2: per-b complex GEMM  img[b,h,w] += sum_p (c[b,p]*Ay[p,h]) * Ax[p,w]
// grid: (NCHUNK, 4 tiles, B). Block: 256 threads, 64x64 tile, 4x4 cplx/thread.
// c folded into the A-tile during LDS staging.
// ---------------------------------------------------------------------------
__global__ __launch_bounds__(256) void gemm_kernel(float* __restrict__ ws) {
    __shared__ float sA[KTILE][128];   // [k][64 cplx]: c*Ay slice
    __shared__ float sB[KTILE][128];   // [k][64 cplx]: Ax slice

    const int chunk = blockIdx.x;           // 0..15
    const int ht    = blockIdx.y >> 1;      // 0..1
    const int wt    = blockIdx.y & 1;       // 0..1
    const int b     = blockIdx.z;           // 0..7
    const int h0 = ht * 64, w0 = wt * 64;
    const int tid = threadIdx.x;
    const int tx = tid & 15;                // w group
    const int ty = tid >> 4;                // h group

    const float* Ay = ws + OFF_AY;
    const float* Ax = ws + OFF_AX;
    const float* cb = ws + OFF_C;

    float accr[4][4] = {{0.f}}, acci[4][4] = {{0.f}};

    for (int kt = 0; kt < KC / KTILE; ++kt) {
        const int p0 = chunk * KC + kt * KTILE;
        // ---- stage KTILE rows of A (c-folded Ay) and B (Ax) ----
#pragma unroll
        for (int pass = 0; pass < 4; ++pass) {
            const int idx = pass * 256 + tid;     // 0..1023
            const int r  = idx >> 5;              // row 0..31
            const int cc = idx & 31;              // float4 column 0..31
            const int p  = p0 + r;

            const float4 bx = *(const float4*)(Ax + (p * 128 + w0) * 2 + cc * 4);
            *(float4*)(&sB[r][cc * 4]) = bx;

            const float4 ay = *(const float4*)(Ay + (p * 128 + h0) * 2 + cc * 4);
            const float cr = cb[p * 16 + 2 * b];
            const float ci = cb[p * 16 + 2 * b + 1];
            float4 av;
            av.x = ay.x * cr - ay.y * ci;
            av.y = ay.x * ci + ay.y * cr;
            av.z = ay.z * cr - ay.w * ci;
            av.w = ay.z * ci + ay.w * cr;
            *(float4*)(&sA[r][cc * 4]) = av;
        }
        __syncthreads();

        // ---- inner product over this K-tile ----
#pragma unroll 8
        for (int k = 0; k < KTILE; ++k) {
            const float2* sAk = (const float2*)(&sA[k][0]);
            const float2* sBk = (const float2*)(&sB[k][0]);
            float2 av[4], bv[4];
#pragma unroll
            for (int j = 0; j < 4; ++j) {
                av[j] = sAk[ty + 16 * j];   // broadcast within wave (4 addrs)
                bv[j] = sBk[tx + 16 * j];   // contiguous 128B, conflict-free
            }
#pragma unroll
            for (int i = 0; i < 4; ++i) {
#pragma unroll
                for (int j = 0; j < 4; ++j) {
                    accr[i][j] = fmaf(av[i].x,  bv[j].x, accr[i][j]);
                    accr[i][j] = fmaf(-av[i].y, bv[j].y, accr[i][j]);
                    acci[i][j] = fmaf(av[i].x,  bv[j].y, acci[i][j]);
                    acci[i][j] = fmaf(av[i].y,  bv[j].x, acci[i][j]);
                }
            }
        }
        __syncthreads();
    }

    // ---- write K-chunk partial ----
    float2* part = (float2*)(ws + OFF_PART);
    const int pbase = (chunk * BATCH + b) * 16384;
#pragma unroll
    for (int i = 0; i < 4; ++i) {
        const int h = h0 + ty + 16 * i;
#pragma unroll
        for (int j = 0; j < 4; ++j) {
            const int w = w0 + tx + 16 * j;
            part[pbase + h * 128 + w] = make_float2(accr[i][j], acci[i][j]);
        }
    }
}

// ---------------------------------------------------------------------------
// Kernel 3: reduce NCHUNK partials -> out (B,1,128,128,2) fp32
// ---------------------------------------------------------------------------
__global__ __launch_bounds__(256) void reduce_kernel(const float* __restrict__ ws,
                                                     float* __restrict__ out) {
    const int i = blockIdx.x * blockDim.x + threadIdx.x;   // 0..131071 (float2 idx)
    const float2* part = (const float2*)(ws + OFF_PART);
    float2 s = part[i];
#pragma unroll
    for (int c = 1; c < NCHUNK; ++c) {
        const float2 v = part[c * 131072 + i];
        s.x += v.x;
        s.y += v.y;
    }
    ((float2*)out)[i] = s;
}

// ---------------------------------------------------------------------------
extern "C" void kernel_launch(void* const* d_in, const int* in_sizes, int n_in,
                              void* d_out, int out_size, void* d_ws, size_t ws_size,
                              hipStream_t stream) {
    const float* ksp  = (const float*)d_in[0];   // (B,1,128,128,2) fp32
    const float* traj = (const float*)d_in[1];   // (4096,2) fp32
    float* out = (float*)d_out;                  // (B,1,128,128,2) fp32
    float* ws  = (float*)d_ws;

    hipLaunchKernelGGL(prep_kernel,   dim3(P_PTS),            dim3(128), 0, stream,
                       ksp, traj, ws);
    hipLaunchKernelGGL(gemm_kernel,   dim3(NCHUNK, 4, BATCH), dim3(256), 0, stream,
                       ws);
    hipLaunchKernelGGL(reduce_kernel, dim3(512),              dim3(256), 0, stream,
                       ws, out);
}

// Round 2
// 83.432 us; speedup vs baseline: 1.4363x; 1.4363x over previous
//
#include <hip/hip_runtime.h>

// Problem constants
#define RES    128
#define P_PTS  4096
#define BATCH  8
#define PHASE  0.04908738521234052f   // 2*pi/128
#define CHUNKS 32                     // K-split

// Workspace byte offsets
//  cb   : float  c[p][8b][2]           256 KB   (c/128, interleaved re/im)
//  Bt   : half   B_t[k8=1024][n=128][8]  2 MB   (Ax, complex-interleaved K)
//  At   : half   A_t[b=8][k8=1024][m=128][8] 16 MB (c-folded Ay)
//  part : half2  part[32][1024*128]     16 MB
// total ~35.9 MB
#define CB_OFF   0u
#define BT_OFF   262144u
#define AT_OFF   2359296u
#define PART_OFF 19136512u

typedef _Float16 half8  __attribute__((ext_vector_type(8)));
typedef _Float16 half2v __attribute__((ext_vector_type(2)));
typedef float    f32x4  __attribute__((ext_vector_type(4)));

// ---------------------------------------------------------------------------
// async global->LDS, 16B per lane. g is per-lane address, lbase is wave-uniform;
// HW writes lbase + lane*16.
// ---------------------------------------------------------------------------
__device__ __forceinline__ void gload16(const void* g, void* lbase, int lane) {
#if defined(__has_builtin) && __has_builtin(__builtin_amdgcn_global_load_lds)
    __builtin_amdgcn_global_load_lds(
        (const __attribute__((address_space(1))) void*)g,
        (__attribute__((address_space(3))) void*)lbase, 16, 0, 0);
#else
    *(float4*)((char*)lbase + lane * 16) = *(const float4*)g;
#endif
}

// ---------------------------------------------------------------------------
// prep1: blocks 0..511 build Bt (Ax table, f16, [k8][n][8] tiled);
//        blocks 512..639 build cb (bilinear grid-sample, scaled 1/128)
// ---------------------------------------------------------------------------
__global__ __launch_bounds__(256) void prep1_kernel(const float* __restrict__ ksp,
                                                    const float* __restrict__ traj,
                                                    float* __restrict__ cb,
                                                    _Float16* __restrict__ Bt) {
    const int idx = blockIdx.x * 256 + threadIdx.x;
    if (blockIdx.x < 512) {
        const int n  = idx & 127;
        const int k8 = idx >> 7;
        const float xs = (float)n - 64.0f;
        half8 v;
#pragma unroll
        for (int q = 0; q < 4; ++q) {
            const int p = k8 * 4 + q;
            float s, c;
            __sincosf(PHASE * traj[2 * p] * xs, &s, &c);
            v[2 * q]     = (_Float16)c;
            v[2 * q + 1] = (_Float16)s;
        }
        *(half8*)(Bt + (size_t)idx * 8) = v;
    } else {
        const int j = idx - 512 * 256;     // 0..32767
        const int p = j >> 3;
        const int b = j & 7;
        const float tx = traj[2 * p], ty = traj[2 * p + 1];
        const float x = tx + 63.5f, y = ty + 63.5f;
        const float x0f = floorf(x), y0f = floorf(y);
        const float wx = x - x0f, wy = y - y0f;
        const int ix0 = (int)x0f, iy0 = (int)y0f;
        float re = 0.0f, im = 0.0f;
#pragma unroll
        for (int dy = 0; dy < 2; ++dy) {
#pragma unroll
            for (int dx = 0; dx < 2; ++dx) {
                const int ix = ix0 + dx, iy = iy0 + dy;
                const float w = (dx ? wx : 1.0f - wx) * (dy ? wy : 1.0f - wy);
                if (ix >= 0 && ix < RES && iy >= 0 && iy < RES) {
                    const int base = ((b * RES + iy) * RES + ix) * 2;
                    re = fmaf(ksp[base],     w, re);
                    im = fmaf(ksp[base + 1], w, im);
                }
            }
        }
        cb[p * 16 + 2 * b]     = re * (1.0f / 128.0f);
        cb[p * 16 + 2 * b + 1] = im * (1.0f / 128.0f);
    }
}

// ---------------------------------------------------------------------------
// prepA: A_t[b][k8][m=h][8] = c[b,p] * exp(i*PHASE*ty_p*(h-64)), f16 pairs
// ---------------------------------------------------------------------------
__global__ __launch_bounds__(256) void prepA_kernel(const float* __restrict__ traj,
                                                    const float* __restrict__ cb,
                                                    _Float16* __restrict__ At) {
    const int idx  = blockIdx.x * 256 + threadIdx.x;  // 0..1048575
    const int m_in = idx & 127;
    const int k8   = (idx >> 7) & 1023;
    const int b    = idx >> 17;
    const float hs = (float)m_in - 64.0f;
    half8 v;
#pragma unroll
    for (int q = 0; q < 4; ++q) {
        const int p = k8 * 4 + q;
        const float cr = cb[p * 16 + 2 * b];
        const float ci = cb[p * 16 + 2 * b + 1];
        float s, c;
        __sincosf(PHASE * traj[2 * p + 1] * hs, &s, &c);
        v[2 * q]     = (_Float16)(cr * c - ci * s);
        v[2 * q + 1] = (_Float16)(cr * s + ci * c);
    }
    *(half8*)(At + (size_t)idx * 8) = v;
}

// ---------------------------------------------------------------------------
// gemm: grid (32 chunks, 8 mb). 256 thr = 4 waves, block tile 128x128,
// wave tile 64x64 via 4x4 mfma_f32_16x16x32_f16, double-buffered LDS with
// async staging and raw-asm barriers (prefetch stays in flight).
// ---------------------------------------------------------------------------
__global__ __launch_bounds__(256) void gemm_kernel(const _Float16* __restrict__ At,
                                                   const _Float16* __restrict__ Bt,
                                                   half2v* __restrict__ part) {
    __shared__ __align__(16) _Float16 sA[2][8192];   // [buf][k8l(8)][m(128)][8]
    __shared__ __align__(16) _Float16 sB[2][8192];   // [buf][k8l(8)][n(128)][8]

    const int chunk = blockIdx.x;
    const int mb    = blockIdx.y;          // == batch b
    const int tid   = threadIdx.x;
    const int wave  = tid >> 6;
    const int lane  = tid & 63;
    const int l15   = lane & 15;
    const int q     = lane >> 4;           // quad 0..3
    const int wm    = wave >> 1;           // 0..1 (M half)
    const int wn    = wave & 1;            // 0..1 (N half)

    const _Float16* aBase = At + (size_t)(mb * 1024 + chunk * 32) * 1024;
    const _Float16* bBase = Bt + (size_t)(chunk * 32) * 1024;

    const half8 SGN = {(_Float16)1.f, (_Float16)-1.f, (_Float16)1.f, (_Float16)-1.f,
                       (_Float16)1.f, (_Float16)-1.f, (_Float16)1.f, (_Float16)-1.f};

    f32x4 accR[4][4], accI[4][4];
#pragma unroll
    for (int i = 0; i < 4; ++i)
#pragma unroll
        for (int j = 0; j < 4; ++j) {
            accR[i][j] = (f32x4){0.f, 0.f, 0.f, 0.f};
            accI[i][j] = (f32x4){0.f, 0.f, 0.f, 0.f};
        }

    auto stage = [&](int r, int buf) {
        // 16 KB A + 16 KB B per round; wave takes subchunks wave*4..wave*4+3
        const _Float16* ga = aBase + r * 8192 + wave * 2048 + lane * 8;
        const _Float16* gb = bBase + r * 8192 + wave * 2048 + lane * 8;
        _Float16* la = &sA[buf][wave * 2048];
        _Float16* lb = &sB[buf][wave * 2048];
#pragma unroll
        for (int i = 0; i < 4; ++i) {
            gload16(ga + i * 512, la + i * 512, lane);
            gload16(gb + i * 512, lb + i * 512, lane);
        }
    };

    auto compute = [&](int buf) {
#pragma unroll
        for (int s = 0; s < 2; ++s) {                    // two K32 steps per round
            const _Float16* pa = &sA[buf][(s * 4 + q) * 1024];
            const _Float16* pb = &sB[buf][(s * 4 + q) * 1024];
            half8 an[4], bv[4], a1[4], a2[4];
#pragma unroll
            for (int t = 0; t < 4; ++t) {
                an[t] = *(const half8*)(pa + (wm * 64 + t * 16 + l15) * 8);
                bv[t] = *(const half8*)(pb + (wn * 64 + t * 16 + l15) * 8);
            }
#pragma unroll
            for (int t = 0; t < 4; ++t) {
                a1[t] = an[t] * SGN;                                     // (ar,-ai)
                a2[t] = __builtin_shufflevector(an[t], an[t],
                                                1, 0, 3, 2, 5, 4, 7, 6); // (ai,ar)
            }
#pragma unroll
            for (int mt = 0; mt < 4; ++mt)
#pragma unroll
                for (int nt = 0; nt < 4; ++nt) {
                    accR[mt][nt] = __builtin_amdgcn_mfma_f32_16x16x32_f16(
                        a1[mt], bv[nt], accR[mt][nt], 0, 0, 0);
                    accI[mt][nt] = __builtin_amdgcn_mfma_f32_16x16x32_f16(
                        a2[mt], bv[nt], accI[mt][nt], 0, 0, 0);
                }
        }
    };

    stage(0, 0);
#pragma unroll
    for (int r = 0; r < 4; ++r) {
        if (r < 3) {
            stage(r + 1, (r + 1) & 1);
            // wait for round r's 8 loads only; keep round r+1's 8 in flight
            asm volatile("s_waitcnt vmcnt(8) lgkmcnt(0)\n\ts_barrier" ::: "memory");
        } else {
            asm volatile("s_waitcnt vmcnt(0) lgkmcnt(0)\n\ts_barrier" ::: "memory");
        }
        compute(r & 1);
        // all waves done reading this buf before next round's stage overwrites
        asm volatile("s_waitcnt lgkmcnt(0)\n\ts_barrier" ::: "memory");
    }

    // epilogue: C/D layout col=lane&15, row=q*4+reg (verified m89/m91)
#pragma unroll
    for (int mt = 0; mt < 4; ++mt) {
#pragma unroll
        for (int nt = 0; nt < 4; ++nt) {
            const int n = wn * 64 + nt * 16 + l15;
#pragma unroll
            for (int rg = 0; rg < 4; ++rg) {
                const int m = mb * 128 + wm * 64 + mt * 16 + q * 4 + rg;
                half2v pv;
                pv[0] = (_Float16)accR[mt][nt][rg];
                pv[1] = (_Float16)accI[mt][nt][rg];
                part[(size_t)chunk * 131072 + m * 128 + n] = pv;
            }
        }
    }
}

// ---------------------------------------------------------------------------
// reduce: sum 32 fp16 partials in fp32 -> out (B,1,128,128,2) fp32
// ---------------------------------------------------------------------------
__global__ __launch_bounds__(256) void reduce_kernel(const half2v* __restrict__ part,
                                                     float2* __restrict__ out) {
    const int i = blockIdx.x * 256 + threadIdx.x;   // 0..131071
    float sr = 0.f, si = 0.f;
#pragma unroll
    for (int c = 0; c < CHUNKS; ++c) {
        half2v v = part[(size_t)c * 131072 + i];
        sr += (float)v[0];
        si += (float)v[1];
    }
    out[i] = make_float2(sr, si);
}

// ---------------------------------------------------------------------------
extern "C" void kernel_launch(void* const* d_in, const int* in_sizes, int n_in,
                              void* d_out, int out_size, void* d_ws, size_t ws_size,
                              hipStream_t stream) {
    const float* ksp  = (const float*)d_in[0];   // (B,1,128,128,2) fp32
    const float* traj = (const float*)d_in[1];   // (4096,2) fp32

    float*     cb   = (float*)((char*)d_ws + CB_OFF);
    _Float16*  Bt   = (_Float16*)((char*)d_ws + BT_OFF);
    _Float16*  At   = (_Float16*)((char*)d_ws + AT_OFF);
    half2v*    part = (half2v*)((char*)d_ws + PART_OFF);

    hipLaunchKernelGGL(prep1_kernel,  dim3(640),        dim3(256), 0, stream,
                       ksp, traj, cb, Bt);
    hipLaunchKernelGGL(prepA_kernel,  dim3(4096),       dim3(256), 0, stream,
                       traj, cb, At);
    hipLaunchKernelGGL(gemm_kernel,   dim3(CHUNKS, 8),  dim3(256), 0, stream,
                       At, Bt, part);
    hipLaunchKernelGGL(reduce_kernel, dim3(512),        dim3(256), 0, stream,
                       part, (float2*)d_out);
}

// Round 3
// 79.640 us; speedup vs baseline: 1.5047x; 1.0476x over previous
//
#include <hip/hip_runtime.h>

// Problem constants
#define RES    128
#define P_PTS  4096
#define BATCH  8
#define CHUNKS 16

// Workspace byte offsets
//  Bt   : half  [k8=1024][n=128][8]           2 MB   (Ax, complex-interleaved K)
//  At   : half  [b=8][k8=1024][m=128][8]     16 MB   (c-folded Ay)
//  part : half2 [16][1024*128]                8 MB
#define BT_OFF   0u
#define AT_OFF   (2u * 1024u * 1024u)
#define PART_OFF (18u * 1024u * 1024u)

typedef _Float16 half8  __attribute__((ext_vector_type(8)));
typedef _Float16 half2v __attribute__((ext_vector_type(2)));
typedef float    f32x4  __attribute__((ext_vector_type(4)));

// ---------------------------------------------------------------------------
// (cos,sin) of 2*pi*rev via native v_fract + v_sin/v_cos (input in revolutions)
// ---------------------------------------------------------------------------
__device__ __forceinline__ float2 phasor(float rev) {
    const float f = rev - floorf(rev);          // exact reduction (fract)
    return make_float2(__builtin_amdgcn_cosf(f), __builtin_amdgcn_sinf(f));
}

// async global->LDS, 16B per lane; lbase wave-uniform, HW scatters lane*16
__device__ __forceinline__ void gload16(const void* g, void* lbase) {
    __builtin_amdgcn_global_load_lds(
        (const __attribute__((address_space(1))) void*)g,
        (__attribute__((address_space(3))) void*)lbase, 16, 0, 0);
}

// ---------------------------------------------------------------------------
// prep: one block per k8 (4 trajectory points). Builds:
//   Bt[k8][n][8]    = Ax phasors
//   At[b][k8][m][8] = c[b,p]/128 * Ay phasors   (c recomputed locally per block)
// ---------------------------------------------------------------------------
__global__ __launch_bounds__(128) void prep_kernel(const float* __restrict__ ksp,
                                                   const float* __restrict__ traj,
                                                   _Float16* __restrict__ Bt,
                                                   _Float16* __restrict__ At) {
    const int k8 = blockIdx.x;       // 0..1023
    const int t  = threadIdx.x;      // 0..127 = grid coordinate (m or n)

    __shared__ float2 sc[4][8];      // c[j][b] / 128

    if (t < 32) {                    // 32 threads: (j,b) grid-sample
        const int j = t >> 3, b = t & 7;
        const int p = k8 * 4 + j;
        const float tx = traj[2 * p], ty = traj[2 * p + 1];
        const float x = tx + 63.5f, y = ty + 63.5f;
        const float x0f = floorf(x), y0f = floorf(y);
        const float wx = x - x0f, wy = y - y0f;
        const int ix0 = (int)x0f, iy0 = (int)y0f;
        float re = 0.0f, im = 0.0f;
#pragma unroll
        for (int dy = 0; dy < 2; ++dy) {
#pragma unroll
            for (int dx = 0; dx < 2; ++dx) {
                const int ix = ix0 + dx, iy = iy0 + dy;
                const float w = (dx ? wx : 1.0f - wx) * (dy ? wy : 1.0f - wy);
                if (ix >= 0 && ix < RES && iy >= 0 && iy < RES) {
                    const int base = ((b * RES + iy) * RES + ix) * 2;
                    re = fmaf(ksp[base],     w, re);
                    im = fmaf(ksp[base + 1], w, im);
                }
            }
        }
        sc[j][b] = make_float2(re * (1.0f / 128.0f), im * (1.0f / 128.0f));
    }
    __syncthreads();

    const float xs = ((float)t - 64.0f) * (1.0f / 128.0f);   // revolutions scale
    float2 ay[4];
    half8 bv;
#pragma unroll
    for (int j = 0; j < 4; ++j) {
        const int p = k8 * 4 + j;
        const float2 ax = phasor(traj[2 * p] * xs);
        ay[j] = phasor(traj[2 * p + 1] * xs);
        bv[2 * j]     = (_Float16)ax.x;
        bv[2 * j + 1] = (_Float16)ax.y;
    }
    *(half8*)(Bt + ((size_t)k8 * 128 + t) * 8) = bv;

#pragma unroll
    for (int b = 0; b < 8; ++b) {
        half8 v;
#pragma unroll
        for (int j = 0; j < 4; ++j) {
            const float cr = sc[j][b].x, ci = sc[j][b].y;
            v[2 * j]     = (_Float16)(cr * ay[j].x - ci * ay[j].y);
            v[2 * j + 1] = (_Float16)(cr * ay[j].y + ci * ay[j].x);
        }
        *(half8*)(At + (((size_t)b * 1024 + k8) * 128 + t) * 8) = v;
    }
}

// ---------------------------------------------------------------------------
// gemm: grid (16 chunks, 16 mtiles = b*2+mhalf). 256 thr = 4 waves.
// Block tile M64 x N128, wave tile 64x32 via 4x2 mfma_f32_16x16x32_f16 (R+I).
// Double-buffered LDS, async staging, prefetch kept in flight (vmcnt(6)).
// ---------------------------------------------------------------------------
__global__ __launch_bounds__(256) void gemm_kernel(const _Float16* __restrict__ At,
                                                   const _Float16* __restrict__ Bt,
                                                   half2v* __restrict__ part) {
    __shared__ __align__(16) _Float16 sA[2][4096];   // [buf][k8l(8)][m(64)][8]
    __shared__ __align__(16) _Float16 sB[2][8192];   // [buf][k8l(8)][n(128)][8]

    const int chunk = blockIdx.x;          // 0..15 : K2 = 1024 per chunk (64 k8)
    const int mt_   = blockIdx.y;          // 0..15
    const int b  = mt_ >> 1;
    const int mh = mt_ & 1;
    const int tid  = threadIdx.x;
    const int wave = tid >> 6;
    const int lane = tid & 63;
    const int l15  = lane & 15;
    const int q    = lane >> 4;

    const _Float16* aCh = At + ((size_t)b * 1024 + chunk * 64) * 1024 + mh * 512;
    const _Float16* bCh = Bt + (size_t)chunk * 64 * 1024;

    const half8 SGN = {(_Float16)1.f, (_Float16)-1.f, (_Float16)1.f, (_Float16)-1.f,
                       (_Float16)1.f, (_Float16)-1.f, (_Float16)1.f, (_Float16)-1.f};

    f32x4 accR[4][2], accI[4][2];
#pragma unroll
    for (int i = 0; i < 4; ++i)
#pragma unroll
        for (int j = 0; j < 2; ++j) {
            accR[i][j] = (f32x4){0.f, 0.f, 0.f, 0.f};
            accI[i][j] = (f32x4){0.f, 0.f, 0.f, 0.f};
        }

    auto stage = [&](int r, int buf) {
        // wave handles k8l = wave*2 + i; each k8 row of A-64 is exactly 1 KB
#pragma unroll
        for (int i = 0; i < 2; ++i) {
            const int k8l = wave * 2 + i;
            const size_t k8o = (size_t)(r * 8 + k8l) * 1024;
            gload16(aCh + k8o + lane * 8, &sA[buf][k8l * 512]);
            gload16(bCh + k8o + lane * 8, &sB[buf][k8l * 1024]);
            gload16(bCh + k8o + 512 + lane * 8, &sB[buf][k8l * 1024 + 512]);
        }
    };

    auto compute = [&](int buf) {
#pragma unroll
        for (int s = 0; s < 2; ++s) {
            const _Float16* pa = &sA[buf][(s * 4 + q) * 512];
            const _Float16* pb = &sB[buf][(s * 4 + q) * 1024];
            half8 an[4], bv[2], a1[4], a2[4];
#pragma unroll
            for (int mt = 0; mt < 4; ++mt)
                an[mt] = *(const half8*)(pa + (mt * 16 + l15) * 8);
#pragma unroll
            for (int nt = 0; nt < 2; ++nt)
                bv[nt] = *(const half8*)(pb + (wave * 32 + nt * 16 + l15) * 8);
#pragma unroll
            for (int mt = 0; mt < 4; ++mt) {
                a1[mt] = an[mt] * SGN;                                     // (ar,-ai)
                a2[mt] = __builtin_shufflevector(an[mt], an[mt],
                                                 1, 0, 3, 2, 5, 4, 7, 6); // (ai,ar)
            }
#pragma unroll
            for (int mt = 0; mt < 4; ++mt)
#pragma unroll
                for (int nt = 0; nt < 2; ++nt) {
                    accR[mt][nt] = __builtin_amdgcn_mfma_f32_16x16x32_f16(
                        a1[mt], bv[nt], accR[mt][nt], 0, 0, 0);
                    accI[mt][nt] = __builtin_amdgcn_mfma_f32_16x16x32_f16(
                        a2[mt], bv[nt], accI[mt][nt], 0, 0, 0);
                }
        }
    };

    stage(0, 0);
#pragma unroll
    for (int r = 0; r < 8; ++r) {
        if (r < 7) {
            stage(r + 1, (r + 1) & 1);
            // drain only round r's 6 loads; round r+1's 6 stay in flight
            asm volatile("s_waitcnt vmcnt(6)\n\ts_barrier" ::: "memory");
        } else {
            asm volatile("s_waitcnt vmcnt(0)\n\ts_barrier" ::: "memory");
        }
        compute(r & 1);
        // all waves done reading this buf before next stage overwrites it
        asm volatile("s_waitcnt lgkmcnt(0)\n\ts_barrier" ::: "memory");
    }

    // epilogue: C/D layout col=lane&15, row=q*4+reg
#pragma unroll
    for (int mt = 0; mt < 4; ++mt) {
#pragma unroll
        for (int nt = 0; nt < 2; ++nt) {
            const int n = wave * 32 + nt * 16 + l15;
#pragma unroll
            for (int rg = 0; rg < 4; ++rg) {
                const int m = b * 128 + mh * 64 + mt * 16 + q * 4 + rg;
                half2v pv;
                pv[0] = (_Float16)accR[mt][nt][rg];
                pv[1] = (_Float16)accI[mt][nt][rg];
                part[(size_t)chunk * 131072 + m * 128 + n] = pv;
            }
        }
    }
}

// ---------------------------------------------------------------------------
// reduce: sum 16 fp16 partials in fp32 -> out (B,1,128,128,2) fp32
// ---------------------------------------------------------------------------
__global__ __launch_bounds__(256) void reduce_kernel(const half2v* __restrict__ part,
                                                     float2* __restrict__ out) {
    const int i = blockIdx.x * 256 + threadIdx.x;   // 0..131071
    float sr = 0.f, si = 0.f;
#pragma unroll
    for (int c = 0; c < CHUNKS; ++c) {
        half2v v = part[(size_t)c * 131072 + i];
        sr += (float)v[0];
        si += (float)v[1];
    }
    out[i] = make_float2(sr, si);
}

// ---------------------------------------------------------------------------
extern "C" void kernel_launch(void* const* d_in, const int* in_sizes, int n_in,
                              void* d_out, int out_size, void* d_ws, size_t ws_size,
                              hipStream_t stream) {
    const float* ksp  = (const float*)d_in[0];   // (B,1,128,128,2) fp32
    const float* traj = (const float*)d_in[1];   // (4096,2) fp32

    _Float16* Bt   = (_Float16*)((char*)d_ws + BT_OFF);
    _Float16* At   = (_Float16*)((char*)d_ws + AT_OFF);
    half2v*   part = (half2v*)((char*)d_ws + PART_OFF);

    hipLaunchKernelGGL(prep_kernel,   dim3(1024),        dim3(128), 0, stream,
                       ksp, traj, Bt, At);
    hipLaunchKernelGGL(gemm_kernel,   dim3(CHUNKS, 16),  dim3(256), 0, stream,
                       At, Bt, part);
    hipLaunchKernelGGL(reduce_kernel, dim3(512),         dim3(256), 0, stream,
                       part, (float2*)d_out);
}

// Round 4
// 74.371 us; speedup vs baseline: 1.6113x; 1.0708x over previous
//
#include <hip/hip_runtime.h>

// Problem constants
#define RES    128
#define P_PTS  4096
#define CHUNKS 16
#define PP     256          // trajectory points per chunk

// Workspace: part half2 [16][1024*128] = 8 MB at offset 0
typedef _Float16 half8  __attribute__((ext_vector_type(8)));
typedef _Float16 half2v __attribute__((ext_vector_type(2)));
typedef float    f32x4  __attribute__((ext_vector_type(4)));

// ---------------------------------------------------------------------------
// fused gemm: grid (16 chunks, 16 = b*2+mh). 256 thr = 4 waves.
// Per block: cache traj + grid-sampled c for its 256 p's in LDS, then
// 8 rounds of {generate sA/sB tiles in LDS via v_sin/v_cos, MFMA}.
// Block tile M64 x N128, wave tile M64 x N32, 4x2 mfma_f32_16x16x32_f16 (R+I).
// No tables, no prep kernel, no global staging traffic.
// ---------------------------------------------------------------------------
__global__ __launch_bounds__(256) void gemm_kernel(const float* __restrict__ ksp,
                                                   const float* __restrict__ traj,
                                                   half2v* __restrict__ part) {
    __shared__ float2 st[PP];                       // (tx, ty) per p
    __shared__ float2 sc[PP];                       // c[b,p]/128
    __shared__ __align__(16) _Float16 sA[4096];     // [k8l(8)][m(64)][8]
    __shared__ __align__(16) _Float16 sB[8192];     // [k8l(8)][n(128)][8]

    const int chunk = blockIdx.x;          // 0..15
    const int b     = blockIdx.y >> 1;     // 0..7
    const int mh    = blockIdx.y & 1;      // 0..1
    const int tid   = threadIdx.x;
    const int wave  = tid >> 6;
    const int lane  = tid & 63;
    const int l15   = lane & 15;
    const int q     = lane >> 4;

    // ---- setup: traj slice + bilinear grid-sample (one p per thread) ----
    {
        const int p = chunk * PP + tid;
        const float tx = traj[2 * p], ty = traj[2 * p + 1];
        st[tid] = make_float2(tx, ty);
        const float x = tx + 63.5f, y = ty + 63.5f;
        const float x0f = floorf(x), y0f = floorf(y);
        const float wx = x - x0f, wy = y - y0f;
        const int ix0 = (int)x0f, iy0 = (int)y0f;
        float re = 0.0f, im = 0.0f;
#pragma unroll
        for (int dy = 0; dy < 2; ++dy) {
#pragma unroll
            for (int dx = 0; dx < 2; ++dx) {
                const int ix = ix0 + dx, iy = iy0 + dy;
                const float w = (dx ? wx : 1.0f - wx) * (dy ? wy : 1.0f - wy);
                if (ix >= 0 && ix < RES && iy >= 0 && iy < RES) {
                    const float2 v = *(const float2*)(ksp + ((b * RES + iy) * RES + ix) * 2);
                    re = fmaf(v.x, w, re);
                    im = fmaf(v.y, w, im);
                }
            }
        }
        sc[tid] = make_float2(re * (1.0f / 128.0f), im * (1.0f / 128.0f));
    }
    __syncthreads();

    f32x4 accR[4][2], accI[4][2];
#pragma unroll
    for (int i = 0; i < 4; ++i)
#pragma unroll
        for (int j = 0; j < 2; ++j) {
            accR[i][j] = (f32x4){0.f, 0.f, 0.f, 0.f};
            accI[i][j] = (f32x4){0.f, 0.f, 0.f, 0.f};
        }

    const float inv = 1.0f / 128.0f;
    const int nB = tid & 127, kB = tid >> 7;    // B-gen: k8l = kB + 2i (wave-uniform)
    const int mA = tid & 63,  kA = tid >> 6;    // A-gen: k8l = kA + 4i (wave-uniform)
    const float xn = ((float)nB - 64.0f) * inv;
    const float xm = ((float)(mh * 64 + mA) - 64.0f) * inv;

    for (int r = 0; r < 8; ++r) {
        const int p0 = r * 32;
        // ---- generate B tile: Ax phasors ----
#pragma unroll
        for (int i = 0; i < 4; ++i) {
            const int k8l = kB + 2 * i;
            half8 v;
#pragma unroll
            for (int j = 0; j < 4; ++j) {
                const int pl = p0 + k8l * 4 + j;       // LDS broadcast (wave-uniform)
                const float rev = st[pl].x * xn;
                const float f = rev - floorf(rev);
                v[2 * j]     = (_Float16)__builtin_amdgcn_cosf(f);
                v[2 * j + 1] = (_Float16)__builtin_amdgcn_sinf(f);
            }
            *(half8*)(sB + ((size_t)(k8l * 128 + nB)) * 8) = v;
        }
        // ---- generate A tile: c-folded Ay phasors ----
#pragma unroll
        for (int i = 0; i < 2; ++i) {
            const int k8l = kA + 4 * i;
            half8 v;
#pragma unroll
            for (int j = 0; j < 4; ++j) {
                const int pl = p0 + k8l * 4 + j;
                const float rev = st[pl].y * xm;
                const float f = rev - floorf(rev);
                const float cs = __builtin_amdgcn_cosf(f);
                const float sn = __builtin_amdgcn_sinf(f);
                const float cr = sc[pl].x, ci = sc[pl].y;
                v[2 * j]     = (_Float16)(cr * cs - ci * sn);
                v[2 * j + 1] = (_Float16)(cr * sn + ci * cs);
            }
            *(half8*)(sA + ((size_t)(k8l * 64 + mA)) * 8) = v;
        }
        __syncthreads();

        // ---- MFMA on the tile ----
#pragma unroll
        for (int s = 0; s < 2; ++s) {
            const _Float16* pa = sA + (s * 4 + q) * 512;
            const _Float16* pb = sB + (s * 4 + q) * 1024;
            half8 an[4], bv[2], a1[4], a2[4];
#pragma unroll
            for (int mt = 0; mt < 4; ++mt)
                an[mt] = *(const half8*)(pa + (mt * 16 + l15) * 8);
#pragma unroll
            for (int nt = 0; nt < 2; ++nt)
                bv[nt] = *(const half8*)(pb + (wave * 32 + nt * 16 + l15) * 8);
            const half8 SGN = {(_Float16)1.f, (_Float16)-1.f, (_Float16)1.f, (_Float16)-1.f,
                               (_Float16)1.f, (_Float16)-1.f, (_Float16)1.f, (_Float16)-1.f};
#pragma unroll
            for (int mt = 0; mt < 4; ++mt) {
                a1[mt] = an[mt] * SGN;                                     // (ar,-ai)
                a2[mt] = __builtin_shufflevector(an[mt], an[mt],
                                                 1, 0, 3, 2, 5, 4, 7, 6); // (ai,ar)
            }
#pragma unroll
            for (int mt = 0; mt < 4; ++mt)
#pragma unroll
                for (int nt = 0; nt < 2; ++nt) {
                    accR[mt][nt] = __builtin_amdgcn_mfma_f32_16x16x32_f16(
                        a1[mt], bv[nt], accR[mt][nt], 0, 0, 0);
                    accI[mt][nt] = __builtin_amdgcn_mfma_f32_16x16x32_f16(
                        a2[mt], bv[nt], accI[mt][nt], 0, 0, 0);
                }
        }
        __syncthreads();
    }

    // ---- epilogue: C/D layout col=lane&15, row=q*4+reg ----
#pragma unroll
    for (int mt = 0; mt < 4; ++mt) {
#pragma unroll
        for (int nt = 0; nt < 2; ++nt) {
            const int n = wave * 32 + nt * 16 + l15;
#pragma unroll
            for (int rg = 0; rg < 4; ++rg) {
                const int m = b * 128 + mh * 64 + mt * 16 + q * 4 + rg;
                half2v pv;
                pv[0] = (_Float16)accR[mt][nt][rg];
                pv[1] = (_Float16)accI[mt][nt][rg];
                part[(size_t)chunk * 131072 + m * 128 + n] = pv;
            }
        }
    }
}

// ---------------------------------------------------------------------------
// reduce: sum 16 fp16 partials in fp32 -> out (B,1,128,128,2) fp32
// ---------------------------------------------------------------------------
__global__ __launch_bounds__(256) void reduce_kernel(const half2v* __restrict__ part,
                                                     float2* __restrict__ out) {
    const int i = blockIdx.x * 256 + threadIdx.x;   // 0..131071
    float sr = 0.f, si = 0.f;
#pragma unroll
    for (int c = 0; c < CHUNKS; ++c) {
        half2v v = part[(size_t)c * 131072 + i];
        sr += (float)v[0];
        si += (float)v[1];
    }
    out[i] = make_float2(sr, si);
}

// ---------------------------------------------------------------------------
extern "C" void kernel_launch(void* const* d_in, const int* in_sizes, int n_in,
                              void* d_out, int out_size, void* d_ws, size_t ws_size,
                              hipStream_t stream) {
    const float* ksp  = (const float*)d_in[0];   // (B,1,128,128,2) fp32
    const float* traj = (const float*)d_in[1];   // (4096,2) fp32
    half2v* part = (half2v*)d_ws;

    hipLaunchKernelGGL(gemm_kernel,   dim3(CHUNKS, 16), dim3(256), 0, stream,
                       ksp, traj, part);
    hipLaunchKernelGGL(reduce_kernel, dim3(512),        dim3(256), 0, stream,
                       part, (float2*)d_out);
}